// Round 1
// baseline (741.445 us; speedup 1.0000x reference)
//
#include <hip/hip_runtime.h>
#include <cstdint>

#define NEG_SLOPE 0.2f
#define EPS 1e-16f

// ---- float <-> order-preserving uint (for atomicMax on floats) ----
// enc is monotone: f1 < f2  <=>  enc(f1) < enc(f2). enc range starts well
// above 0, so memset(0) == "-inf" init (every node has a self-loop, so every
// slot gets at least one real update before decode).
__device__ __forceinline__ unsigned enc_f(float f) {
    unsigned b = __float_as_uint(f);
    return (b & 0x80000000u) ? ~b : (b | 0x80000000u);
}
__device__ __forceinline__ float dec_f(unsigned u) {
    unsigned b = (u & 0x80000000u) ? (u & 0x7FFFFFFFu) : ~u;
    return __uint_as_float(b);
}

__device__ __forceinline__ float lrelu(float x) {
    return (x >= 0.f) ? x : NEG_SLOPE * x;
}

// ---- Layer 1 node kernel: h1 = x @ W1^T, a_src/a_dst dot products ----
// one wave (64 lanes) per node; lane j owns feature j.
__global__ void node1_kernel(const float* __restrict__ x,
                             const float* __restrict__ W1,
                             const float* __restrict__ att_s,
                             const float* __restrict__ att_d,
                             float* __restrict__ h1,
                             float* __restrict__ asrc,
                             float* __restrict__ adst, int N) {
    int gid = blockIdx.x * blockDim.x + threadIdx.x;
    int n = gid >> 6;
    int j = gid & 63;
    if (n >= N) return;
    float x0 = x[2 * n], x1 = x[2 * n + 1];
    float h = x0 * W1[2 * j] + x1 * W1[2 * j + 1];
    h1[n * 64 + j] = h;
    float ps = h * att_s[j];
    float pd = h * att_d[j];
    #pragma unroll
    for (int m = 32; m; m >>= 1) {
        ps += __shfl_xor(ps, m);
        pd += __shfl_xor(pd, m);
    }
    if (j == 0) { asrc[n] = ps; adst[n] = pd; }
}

// ---- edge pass 1: segment max over dst ----
__global__ void edge_max_kernel(const int* __restrict__ src,
                                const int* __restrict__ dst,
                                const float* __restrict__ asrc,
                                const float* __restrict__ adst,
                                unsigned* __restrict__ menc, int E, int Etot) {
    int i = blockIdx.x * blockDim.x + threadIdx.x;
    if (i >= Etot) return;
    int s = (i < E) ? src[i] : (i - E);
    int d = (i < E) ? dst[i] : (i - E);
    float e = lrelu(asrc[s] + adst[d]);
    atomicMax(menc + d, enc_f(e));
}

// ---- edge pass 2: ex = exp(e - m[dst]); denom = segment_sum(ex) ----
__global__ void edge_exp_kernel(const int* __restrict__ src,
                                const int* __restrict__ dst,
                                const float* __restrict__ asrc,
                                const float* __restrict__ adst,
                                const unsigned* __restrict__ menc,
                                float* __restrict__ ex,
                                float* __restrict__ denom, int E, int Etot) {
    int i = blockIdx.x * blockDim.x + threadIdx.x;
    if (i >= Etot) return;
    int s = (i < E) ? src[i] : (i - E);
    int d = (i < E) ? dst[i] : (i - E);
    float e = lrelu(asrc[s] + adst[d]);
    float v = expf(e - dec_f(menc[d]));
    ex[i] = v;
    atomicAdd(denom + d, v);
}

// ---- edge pass 3 (layer 1): agg[dst] += h1[src] * alpha, 64 feats ----
// one wave per edge: lane j owns feature j -> coalesced gather + coalesced
// atomic target (256B contiguous per wave).
__global__ void edge_agg64_kernel(const int* __restrict__ src,
                                  const int* __restrict__ dst,
                                  const float* __restrict__ ex,
                                  const float* __restrict__ denom,
                                  const float* __restrict__ h1,
                                  float* __restrict__ agg, int E, int Etot) {
    int gid = blockIdx.x * blockDim.x + threadIdx.x;
    int i = gid >> 6;
    int j = gid & 63;
    if (i >= Etot) return;
    int s = (i < E) ? src[i] : (i - E);
    int d = (i < E) ? dst[i] : (i - E);
    float alpha = ex[i] / (denom[d] + EPS);
    atomicAdd(agg + (size_t)d * 64 + j, h1[(size_t)s * 64 + j] * alpha);
}

// ---- Layer 2 node kernel: hr = relu(agg1 + b1); h2 = hr @ W2^T; a_* ----
__global__ void node2_kernel(const float* __restrict__ agg1,
                             const float* __restrict__ b1,
                             const float* __restrict__ W2,
                             const float* __restrict__ att_s2,
                             const float* __restrict__ att_d2,
                             float* __restrict__ h2,
                             float* __restrict__ asrc,
                             float* __restrict__ adst, int N) {
    int gid = blockIdx.x * blockDim.x + threadIdx.x;
    int n = gid >> 6;
    int j = gid & 63;
    if (n >= N) return;
    float hr = fmaxf(agg1[n * 64 + j] + b1[j], 0.f);
    float p0 = hr * W2[j];
    float p1 = hr * W2[64 + j];
    #pragma unroll
    for (int m = 32; m; m >>= 1) {
        p0 += __shfl_xor(p0, m);
        p1 += __shfl_xor(p1, m);
    }
    if (j == 0) {
        h2[2 * n] = p0;
        h2[2 * n + 1] = p1;
        asrc[n] = p0 * att_s2[0] + p1 * att_s2[1];
        adst[n] = p0 * att_d2[0] + p1 * att_d2[1];
    }
}

// ---- edge pass 3 (layer 2): 2 features per edge, thread per edge ----
__global__ void edge_agg2_kernel(const int* __restrict__ src,
                                 const int* __restrict__ dst,
                                 const float* __restrict__ ex,
                                 const float* __restrict__ denom,
                                 const float* __restrict__ h2,
                                 float* __restrict__ agg, int E, int Etot) {
    int i = blockIdx.x * blockDim.x + threadIdx.x;
    if (i >= Etot) return;
    int s = (i < E) ? src[i] : (i - E);
    int d = (i < E) ? dst[i] : (i - E);
    float alpha = ex[i] / (denom[d] + EPS);
    atomicAdd(agg + 2 * d,     h2[2 * s] * alpha);
    atomicAdd(agg + 2 * d + 1, h2[2 * s + 1] * alpha);
}

// ---- final: log_softmax over 2 cols, in place on d_out ----
__global__ void finalize_kernel(const float* __restrict__ b2,
                                float* __restrict__ out, int N) {
    int n = blockIdx.x * blockDim.x + threadIdx.x;
    if (n >= N) return;
    float v0 = out[2 * n] + b2[0];
    float v1 = out[2 * n + 1] + b2[1];
    float mx = fmaxf(v0, v1);
    float lse = mx + logf(expf(v0 - mx) + expf(v1 - mx));
    out[2 * n] = v0 - lse;
    out[2 * n + 1] = v1 - lse;
}

extern "C" void kernel_launch(void* const* d_in, const int* in_sizes, int n_in,
                              void* d_out, int out_size, void* d_ws, size_t ws_size,
                              hipStream_t stream) {
    const float* x        = (const float*)d_in[0];
    const int*   eidx     = (const int*)d_in[1];
    const float* W1       = (const float*)d_in[2];
    const float* att_s1   = (const float*)d_in[3];
    const float* att_d1   = (const float*)d_in[4];
    const float* b1       = (const float*)d_in[5];
    const float* W2       = (const float*)d_in[6];
    const float* att_s2   = (const float*)d_in[7];
    const float* att_d2   = (const float*)d_in[8];
    const float* b2       = (const float*)d_in[9];

    const int N    = in_sizes[0] / 2;       // x is [N,2]
    const int E    = in_sizes[1] / 2;       // edge_index is [2,E]
    const int Etot = E + N;                 // + self loops

    const int* src = eidx;
    const int* dst = eidx + E;

    // ---- workspace carve-up (floats) ----
    char* w = (char*)d_ws;
    float*    h1    = (float*)w;                 w += (size_t)N * 64 * 4;
    float*    agg1  = (float*)w;                 w += (size_t)N * 64 * 4;
    float*    asrc  = (float*)w;                 w += (size_t)N * 4;
    float*    adst  = (float*)w;                 w += (size_t)N * 4;
    unsigned* menc  = (unsigned*)w;              w += (size_t)N * 4;
    float*    denom = (float*)w;                 w += (size_t)N * 4;
    float*    ex    = (float*)w;                 w += (size_t)Etot * 4;
    float*    h2    = (float*)w;                 w += (size_t)N * 2 * 4;
    float*    out   = (float*)d_out;             // agg2 accumulates here

    // ---- zero the accumulators (enc(0)=min, so memset doubles as -inf) ----
    hipMemsetAsync(agg1,  0, (size_t)N * 64 * 4, stream);
    hipMemsetAsync(menc,  0, (size_t)N * 4, stream);
    hipMemsetAsync(denom, 0, (size_t)N * 4, stream);
    hipMemsetAsync(out,   0, (size_t)N * 2 * 4, stream);

    const int B = 256;
    dim3 blk(B);

    // ---- layer 1 ----
    node1_kernel<<<dim3((N * 64 + B - 1) / B), blk, 0, stream>>>(
        x, W1, att_s1, att_d1, h1, asrc, adst, N);
    edge_max_kernel<<<dim3((Etot + B - 1) / B), blk, 0, stream>>>(
        src, dst, asrc, adst, menc, E, Etot);
    edge_exp_kernel<<<dim3((Etot + B - 1) / B), blk, 0, stream>>>(
        src, dst, asrc, adst, menc, ex, denom, E, Etot);
    edge_agg64_kernel<<<dim3(((size_t)Etot * 64 + B - 1) / B), blk, 0, stream>>>(
        src, dst, ex, denom, h1, agg1, E, Etot);

    // ---- reset per-layer accumulators for layer 2 ----
    hipMemsetAsync(menc,  0, (size_t)N * 4, stream);
    hipMemsetAsync(denom, 0, (size_t)N * 4, stream);

    // ---- layer 2 ----
    node2_kernel<<<dim3((N * 64 + B - 1) / B), blk, 0, stream>>>(
        agg1, b1, W2, att_s2, att_d2, h2, asrc, adst, N);
    edge_max_kernel<<<dim3((Etot + B - 1) / B), blk, 0, stream>>>(
        src, dst, asrc, adst, menc, E, Etot);
    edge_exp_kernel<<<dim3((Etot + B - 1) / B), blk, 0, stream>>>(
        src, dst, asrc, adst, menc, ex, denom, E, Etot);
    edge_agg2_kernel<<<dim3((Etot + B - 1) / B), blk, 0, stream>>>(
        src, dst, ex, denom, h2, out, E, Etot);

    // ---- log_softmax (in place on d_out) ----
    finalize_kernel<<<dim3((N + B - 1) / B), blk, 0, stream>>>(b2, out, N);
}

// Round 2
// 295.286 us; speedup vs baseline: 2.5109x; 2.5109x over previous
//
#include <hip/hip_runtime.h>
#include <cstdint>

#define NEG_SLOPE 0.2f
#define EPS 1e-16f
#define SCAN_B 256

__device__ __forceinline__ float lrelu(float x) {
    return (x >= 0.f) ? x : NEG_SLOPE * x;
}
__device__ __forceinline__ float wave_sum(float v) {
    #pragma unroll
    for (int o = 32; o; o >>= 1) v += __shfl_xor(v, o);
    return v;
}
__device__ __forceinline__ float wave_max(float v) {
    #pragma unroll
    for (int o = 32; o; o >>= 1) v = fmaxf(v, __shfl_xor(v, o));
    return v;
}

// ================= CSR build =================
__global__ void deg_kernel(const int* __restrict__ dst, int* __restrict__ deg,
                           int E, int Etot) {
    int i = blockIdx.x * blockDim.x + threadIdx.x;
    if (i >= Etot) return;
    int d = (i < E) ? dst[i] : (i - E);
    atomicAdd(deg + d, 1);
}

// per-block inclusive scan of deg -> incl, block totals -> bsum
__global__ void scan_block_kernel(const int* __restrict__ deg,
                                  int* __restrict__ incl,
                                  int* __restrict__ bsum, int N) {
    __shared__ int s[SCAN_B];
    int i = blockIdx.x * SCAN_B + threadIdx.x;
    int v = (i < N) ? deg[i] : 0;
    s[threadIdx.x] = v;
    __syncthreads();
    #pragma unroll
    for (int off = 1; off < SCAN_B; off <<= 1) {
        int t = (threadIdx.x >= off) ? s[threadIdx.x - off] : 0;
        __syncthreads();
        s[threadIdx.x] += t;
        __syncthreads();
    }
    if (i < N) incl[i] = s[threadIdx.x];
    if (threadIdx.x == SCAN_B - 1) bsum[blockIdx.x] = s[threadIdx.x];
}

// single-block exclusive scan over block sums (nb <= 1024)
__global__ void scan_partials_kernel(int* __restrict__ bsum, int nb) {
    __shared__ int s[1024];
    int v = (threadIdx.x < nb) ? bsum[threadIdx.x] : 0;
    s[threadIdx.x] = v;
    __syncthreads();
    #pragma unroll
    for (int off = 1; off < 1024; off <<= 1) {
        int t = (threadIdx.x >= off) ? s[threadIdx.x - off] : 0;
        __syncthreads();
        s[threadIdx.x] += t;
        __syncthreads();
    }
    if (threadIdx.x < nb) bsum[threadIdx.x] = s[threadIdx.x] - v;  // exclusive
}

__global__ void rowptr_kernel(const int* __restrict__ deg,
                              const int* __restrict__ incl,
                              const int* __restrict__ bsum,
                              int* __restrict__ rowptr, int N, int Etot) {
    int i = blockIdx.x * blockDim.x + threadIdx.x;
    if (i < N) rowptr[i] = incl[i] - deg[i] + bsum[i / SCAN_B];
    if (i == 0) rowptr[N] = Etot;
}

__global__ void scatter_kernel(const int* __restrict__ src,
                               const int* __restrict__ dst,
                               const int* __restrict__ rowptr,
                               int* __restrict__ cursor,
                               int* __restrict__ csr_src, int E, int Etot) {
    int i = blockIdx.x * blockDim.x + threadIdx.x;
    if (i >= Etot) return;
    int s, d;
    if (i < E) { s = src[i]; d = dst[i]; } else { s = d = i - E; }
    int pos = rowptr[d] + atomicAdd(cursor + d, 1);
    csr_src[pos] = s;
}

// ================= layer 1 node transform =================
// one wave per node; lane j owns feature j of h1.
__global__ void node1_kernel(const float* __restrict__ x,
                             const float* __restrict__ W1,
                             const float* __restrict__ att_s,
                             const float* __restrict__ att_d,
                             float* __restrict__ h1,
                             float* __restrict__ asrc,
                             float* __restrict__ adst, int N) {
    int gid = blockIdx.x * blockDim.x + threadIdx.x;
    int n = gid >> 6;
    int j = gid & 63;
    if (n >= N) return;
    float x0 = x[2 * n], x1 = x[2 * n + 1];
    float h = x0 * W1[2 * j] + x1 * W1[2 * j + 1];
    h1[(size_t)n * 64 + j] = h;
    float ps = wave_sum(h * att_s[j]);
    float pd = wave_sum(h * att_d[j]);
    if (j == 0) { asrc[n] = ps; adst[n] = pd; }
}

// ================= fused layer-1 aggregation + layer-2 node transform ======
// one wave per dst node. softmax over incoming edges, gather h1[src],
// accumulate in registers, then relu+b1, @W2^T, att2 dots — all fused.
__global__ void fused_agg1_kernel(const int* __restrict__ rowptr,
                                  const int* __restrict__ csr_src,
                                  const float* __restrict__ asrc,
                                  const float* __restrict__ adst,
                                  const float* __restrict__ h1,
                                  const float* __restrict__ b1,
                                  const float* __restrict__ W2,
                                  const float* __restrict__ as2,
                                  const float* __restrict__ ad2,
                                  float* __restrict__ h2,
                                  float* __restrict__ asrc2,
                                  float* __restrict__ adst2, int N) {
    int gid = blockIdx.x * blockDim.x + threadIdx.x;
    int n = gid >> 6;
    int lane = gid & 63;
    if (n >= N) return;
    int start = rowptr[n], end = rowptr[n + 1];
    float adst_n = adst[n];

    // phase 1a: per-lane e over strided edges; cache e of edge (start+lane)
    float e0 = -INFINITY;
    float m = -INFINITY;
    for (int k = start + lane; k < end; k += 64) {
        int s = csr_src[k];
        float ev = lrelu(asrc[s] + adst_n);
        if (k - start < 64) e0 = ev;
        m = fmaxf(m, ev);
    }
    m = wave_max(m);  // every node has a self-loop -> m finite

    // phase 1b: exp + denom (recompute only for edges beyond the first 64)
    float pexp = __expf(e0 - m);  // 0 for lanes without an edge
    float psum = pexp;
    for (int k = start + 64 + lane; k < end; k += 64) {
        int s = csr_src[k];
        psum += __expf(lrelu(asrc[s] + adst_n) - m);
    }
    float rdenom = 1.f / (wave_sum(psum) + EPS);

    // phase 2: serial over edges; lane j accumulates feature j
    float acc = 0.f;
    int k = start;
    for (; k + 1 < end; k += 2) {
        int idx = k - start;
        int s0 = csr_src[k], s1 = csr_src[k + 1];
        float pv0, pv1;
        if (idx + 1 < 64) {
            pv0 = __shfl(pexp, idx);
            pv1 = __shfl(pexp, idx + 1);
        } else {
            pv0 = __expf(lrelu(asrc[s0] + adst_n) - m);
            pv1 = __expf(lrelu(asrc[s1] + adst_n) - m);
        }
        float g0 = h1[(size_t)s0 * 64 + lane];
        float g1 = h1[(size_t)s1 * 64 + lane];
        acc = fmaf(pv0, g0, acc);
        acc = fmaf(pv1, g1, acc);
    }
    if (k < end) {
        int idx = k - start;
        int s0 = csr_src[k];
        float pv0 = (idx < 64) ? __shfl(pexp, idx)
                               : __expf(lrelu(asrc[s0] + adst_n) - m);
        acc = fmaf(pv0, h1[(size_t)s0 * 64 + lane], acc);
    }
    acc *= rdenom;

    // fused node2: hr = relu(acc + b1); h2 = hr @ W2^T; att2 dots
    float hr = fmaxf(acc + b1[lane], 0.f);
    float q0 = wave_sum(hr * W2[lane]);
    float q1 = wave_sum(hr * W2[64 + lane]);
    if (lane == 0) {
        h2[2 * n] = q0;
        h2[2 * n + 1] = q1;
        asrc2[n] = q0 * as2[0] + q1 * as2[1];
        adst2[n] = q0 * ad2[0] + q1 * ad2[1];
    }
}

// ================= fused layer-2 aggregation + bias + log_softmax ==========
// one wave per dst node; lanes parallel over edges.
__global__ void fused_agg2_kernel(const int* __restrict__ rowptr,
                                  const int* __restrict__ csr_src,
                                  const float* __restrict__ asrc2,
                                  const float* __restrict__ adst2,
                                  const float* __restrict__ h2,
                                  const float* __restrict__ b2,
                                  float* __restrict__ out, int N) {
    int gid = blockIdx.x * blockDim.x + threadIdx.x;
    int n = gid >> 6;
    int lane = gid & 63;
    if (n >= N) return;
    int start = rowptr[n], end = rowptr[n + 1];
    float adst_n = adst2[n];

    float m = -INFINITY;
    for (int k = start + lane; k < end; k += 64) {
        int s = csr_src[k];
        m = fmaxf(m, lrelu(asrc2[s] + adst_n));
    }
    m = wave_max(m);

    float psum = 0.f, acc0 = 0.f, acc1 = 0.f;
    for (int k = start + lane; k < end; k += 64) {
        int s = csr_src[k];
        float pv = __expf(lrelu(asrc2[s] + adst_n) - m);
        psum += pv;
        acc0 = fmaf(pv, h2[2 * s], acc0);
        acc1 = fmaf(pv, h2[2 * s + 1], acc1);
    }
    psum = wave_sum(psum);
    acc0 = wave_sum(acc0);
    acc1 = wave_sum(acc1);

    if (lane == 0) {
        float rd = 1.f / (psum + EPS);
        float v0 = acc0 * rd + b2[0];
        float v1 = acc1 * rd + b2[1];
        float mx = fmaxf(v0, v1);
        float lse = mx + logf(__expf(v0 - mx) + __expf(v1 - mx));
        out[2 * n] = v0 - lse;
        out[2 * n + 1] = v1 - lse;
    }
}

extern "C" void kernel_launch(void* const* d_in, const int* in_sizes, int n_in,
                              void* d_out, int out_size, void* d_ws, size_t ws_size,
                              hipStream_t stream) {
    const float* x      = (const float*)d_in[0];
    const int*   eidx   = (const int*)d_in[1];
    const float* W1     = (const float*)d_in[2];
    const float* att_s1 = (const float*)d_in[3];
    const float* att_d1 = (const float*)d_in[4];
    const float* b1     = (const float*)d_in[5];
    const float* W2     = (const float*)d_in[6];
    const float* att_s2 = (const float*)d_in[7];
    const float* att_d2 = (const float*)d_in[8];
    const float* b2     = (const float*)d_in[9];

    const int N    = in_sizes[0] / 2;   // x is [N,2]
    const int E    = in_sizes[1] / 2;   // edge_index is [2,E]
    const int Etot = E + N;             // + self loops
    const int nb   = (N + SCAN_B - 1) / SCAN_B;   // scan blocks (must be <=1024)

    const int* src = eidx;
    const int* dst = eidx + E;

    // ---- workspace carve-up ----
    char* w = (char*)d_ws;
    int*   deg     = (int*)w;      w += (size_t)N * 4;
    int*   cursor  = (int*)w;      w += (size_t)N * 4;
    int*   incl    = (int*)w;      w += (size_t)N * 4;
    int*   bsum    = (int*)w;      w += (size_t)1024 * 4;
    int*   rowptr  = (int*)w;      w += (size_t)(N + 1) * 4;
    int*   csr_src = (int*)w;      w += (size_t)Etot * 4;
    float* h1      = (float*)w;    w += (size_t)N * 64 * 4;
    float* asrc    = (float*)w;    w += (size_t)N * 4;
    float* adst    = (float*)w;    w += (size_t)N * 4;
    float* h2      = (float*)w;    w += (size_t)N * 2 * 4;
    float* asrc2   = (float*)w;    w += (size_t)N * 4;
    float* adst2   = (float*)w;    w += (size_t)N * 4;
    float* out     = (float*)d_out;

    hipMemsetAsync(deg, 0, (size_t)N * 2 * 4, stream);  // deg + cursor (adjacent)

    const int B = 256;
    dim3 blk(B);
    auto g1 = [&](long long t) { return dim3((unsigned)((t + B - 1) / B)); };

    // ---- CSR build ----
    deg_kernel<<<g1(Etot), blk, 0, stream>>>(dst, deg, E, Etot);
    scan_block_kernel<<<dim3(nb), dim3(SCAN_B), 0, stream>>>(deg, incl, bsum, N);
    scan_partials_kernel<<<dim3(1), dim3(1024), 0, stream>>>(bsum, nb);
    rowptr_kernel<<<g1(N + 1), blk, 0, stream>>>(deg, incl, bsum, rowptr, N, Etot);
    scatter_kernel<<<g1(Etot), blk, 0, stream>>>(src, dst, rowptr, cursor, csr_src, E, Etot);

    // ---- layer 1 ----
    node1_kernel<<<g1((long long)N * 64), blk, 0, stream>>>(
        x, W1, att_s1, att_d1, h1, asrc, adst, N);
    fused_agg1_kernel<<<g1((long long)N * 64), blk, 0, stream>>>(
        rowptr, csr_src, asrc, adst, h1, b1, W2, att_s2, att_d2,
        h2, asrc2, adst2, N);

    // ---- layer 2 (+ bias + log_softmax) ----
    fused_agg2_kernel<<<g1((long long)N * 64), blk, 0, stream>>>(
        rowptr, csr_src, asrc2, adst2, h2, b2, out, N);
}

// Round 3
// 257.061 us; speedup vs baseline: 2.8843x; 1.1487x over previous
//
#include <hip/hip_runtime.h>
#include <cstdint>

#define NEG_SLOPE 0.2f
#define EPS 1e-16f
#define SCAN_B 256

__device__ __forceinline__ float lrelu(float x) {
    return (x >= 0.f) ? x : NEG_SLOPE * x;
}
__device__ __forceinline__ float wave_sum(float v) {
    #pragma unroll
    for (int o = 32; o; o >>= 1) v += __shfl_xor(v, o);
    return v;
}
__device__ __forceinline__ float wave_max(float v) {
    #pragma unroll
    for (int o = 32; o; o >>= 1) v = fmaxf(v, __shfl_xor(v, o));
    return v;
}

// ================= CSR build =================
__global__ void deg_kernel(const int* __restrict__ dst, int* __restrict__ deg,
                           int E, int Etot) {
    int i = blockIdx.x * blockDim.x + threadIdx.x;
    if (i >= Etot) return;
    int d = (i < E) ? dst[i] : (i - E);
    atomicAdd(deg + d, 1);
}

__global__ void scan_block_kernel(const int* __restrict__ deg,
                                  int* __restrict__ incl,
                                  int* __restrict__ bsum, int N) {
    __shared__ int s[SCAN_B];
    int i = blockIdx.x * SCAN_B + threadIdx.x;
    int v = (i < N) ? deg[i] : 0;
    s[threadIdx.x] = v;
    __syncthreads();
    #pragma unroll
    for (int off = 1; off < SCAN_B; off <<= 1) {
        int t = (threadIdx.x >= off) ? s[threadIdx.x - off] : 0;
        __syncthreads();
        s[threadIdx.x] += t;
        __syncthreads();
    }
    if (i < N) incl[i] = s[threadIdx.x];
    if (threadIdx.x == SCAN_B - 1) bsum[blockIdx.x] = s[threadIdx.x];
}

__global__ void scan_partials_kernel(int* __restrict__ bsum, int nb) {
    __shared__ int s[1024];
    int v = (threadIdx.x < nb) ? bsum[threadIdx.x] : 0;
    s[threadIdx.x] = v;
    __syncthreads();
    #pragma unroll
    for (int off = 1; off < 1024; off <<= 1) {
        int t = (threadIdx.x >= off) ? s[threadIdx.x - off] : 0;
        __syncthreads();
        s[threadIdx.x] += t;
        __syncthreads();
    }
    if (threadIdx.x < nb) bsum[threadIdx.x] = s[threadIdx.x] - v;  // exclusive
}

__global__ void rowptr_kernel(const int* __restrict__ deg,
                              const int* __restrict__ incl,
                              const int* __restrict__ bsum,
                              int* __restrict__ rowptr, int N, int Etot) {
    int i = blockIdx.x * blockDim.x + threadIdx.x;
    if (i < N) rowptr[i] = incl[i] - deg[i] + bsum[i / SCAN_B];
    if (i == 0) rowptr[N] = Etot;
}

__global__ void scatter_kernel(const int* __restrict__ src,
                               const int* __restrict__ dst,
                               const int* __restrict__ rowptr,
                               int* __restrict__ cursor,
                               int* __restrict__ csr_src, int E, int Etot) {
    int i = blockIdx.x * blockDim.x + threadIdx.x;
    if (i >= Etot) return;
    int s, d;
    if (i < E) { s = src[i]; d = dst[i]; } else { s = d = i - E; }
    int pos = rowptr[d] + atomicAdd(cursor + d, 1);
    csr_src[pos] = s;
}

// ================= layer 1 node pack: {x0, x1, a_src1, a_dst1} =============
__global__ void node1_kernel(const float* __restrict__ x,
                             const float* __restrict__ W1,
                             const float* __restrict__ att_s,
                             const float* __restrict__ att_d,
                             float4* __restrict__ pack1, int N) {
    int gid = blockIdx.x * blockDim.x + threadIdx.x;
    int n = gid >> 6;
    int j = gid & 63;
    if (n >= N) return;
    float x0 = x[2 * n], x1 = x[2 * n + 1];
    float h = x0 * W1[2 * j] + x1 * W1[2 * j + 1];
    float ps = wave_sum(h * att_s[j]);
    float pd = wave_sum(h * att_d[j]);
    if (j == 0) pack1[n] = make_float4(x0, x1, ps, pd);
}

// ====== fused layer-1 aggregation (h1 recomputed in-register) + node2 ======
// one wave per dst node. lane l caches edge (start+l)'s {x0,x1,pexp};
// phase B broadcasts them by shuffle — no memory ops in the inner loop.
__global__ void fused_agg1_kernel(const int* __restrict__ rowptr,
                                  const int* __restrict__ csr_src,
                                  const float4* __restrict__ pack1,
                                  const float* __restrict__ W1,
                                  const float* __restrict__ b1,
                                  const float* __restrict__ W2,
                                  const float* __restrict__ as2,
                                  const float* __restrict__ ad2,
                                  float4* __restrict__ pack2, int N) {
    int gid = blockIdx.x * blockDim.x + threadIdx.x;
    int n = gid >> 6;
    int lane = gid & 63;
    if (n >= N) return;
    int start = rowptr[n], end = rowptr[n + 1];
    int deg = end - start;
    float adst_n = ((const float*)(pack1 + n))[3];

    // phase A: lane l owns edge start+l
    float4 p = make_float4(0.f, 0.f, 0.f, 0.f);
    float e = -INFINITY;
    if (lane < deg) {
        int s = csr_src[start + lane];
        p = pack1[s];
        e = lrelu(p.z + adst_n);
    }
    float m = e;
    // tail max (deg > 64, rare)
    for (int k = start + 64 + lane; k < end; k += 64) {
        int s = csr_src[k];
        m = fmaxf(m, lrelu(((const float*)(pack1 + s))[2] + adst_n));
    }
    m = wave_max(m);  // self-loop guarantees finite

    float pexp = __expf(e - m);     // 0 for pad lanes
    float psum = pexp;
    for (int k = start + 64 + lane; k < end; k += 64) {
        int s = csr_src[k];
        psum += __expf(lrelu(((const float*)(pack1 + s))[2] + adst_n) - m);
    }
    float rdenom = 1.f / (wave_sum(psum) + EPS);

    // phase B: serial over edges, all in-register (lane owns feature `lane`)
    float w0 = W1[2 * lane], w1 = W1[2 * lane + 1];
    float acc = 0.f;
    int nin = (deg < 64) ? deg : 64;
    for (int idx = 0; idx < nin; ++idx) {
        float x0 = __shfl(p.x, idx);
        float x1 = __shfl(p.y, idx);
        float pv = __shfl(pexp, idx);
        float h = fmaf(x0, w0, x1 * w1);
        acc = fmaf(pv, h, acc);
    }
    // tail (deg > 64): uniform gathers, every lane loads the same address
    for (int k = start + 64; k < end; ++k) {
        int s = csr_src[k];
        float4 q = pack1[s];
        float pv = __expf(lrelu(q.z + adst_n) - m);
        acc = fmaf(pv, fmaf(q.x, w0, q.y * w1), acc);
    }
    acc *= rdenom;

    // fused node2: hr = relu(acc + b1); h2 = hr @ W2^T; att2 dots
    float hr = fmaxf(acc + b1[lane], 0.f);
    float q0 = wave_sum(hr * W2[lane]);
    float q1 = wave_sum(hr * W2[64 + lane]);
    if (lane == 0)
        pack2[n] = make_float4(q0, q1,
                               q0 * as2[0] + q1 * as2[1],
                               q0 * ad2[0] + q1 * ad2[1]);
}

// ====== fused layer-2 aggregation + bias + log_softmax (lane-parallel) =====
__global__ void fused_agg2_kernel(const int* __restrict__ rowptr,
                                  const int* __restrict__ csr_src,
                                  const float4* __restrict__ pack2,
                                  const float* __restrict__ b2,
                                  float* __restrict__ out, int N) {
    int gid = blockIdx.x * blockDim.x + threadIdx.x;
    int n = gid >> 6;
    int lane = gid & 63;
    if (n >= N) return;
    int start = rowptr[n], end = rowptr[n + 1];
    int deg = end - start;
    float adst_n = ((const float*)(pack2 + n))[3];

    float4 p = make_float4(0.f, 0.f, 0.f, 0.f);
    float e = -INFINITY;
    if (lane < deg) {
        int s = csr_src[start + lane];
        p = pack2[s];
        e = lrelu(p.z + adst_n);
    }
    float m = e;
    for (int k = start + 64 + lane; k < end; k += 64) {
        int s = csr_src[k];
        m = fmaxf(m, lrelu(((const float*)(pack2 + s))[2] + adst_n));
    }
    m = wave_max(m);

    float pe = __expf(e - m);
    float psum = pe, acc0 = pe * p.x, acc1 = pe * p.y;
    for (int k = start + 64 + lane; k < end; k += 64) {
        int s = csr_src[k];
        float4 q = pack2[s];
        float t = __expf(lrelu(q.z + adst_n) - m);
        psum += t;
        acc0 = fmaf(t, q.x, acc0);
        acc1 = fmaf(t, q.y, acc1);
    }
    psum = wave_sum(psum);
    acc0 = wave_sum(acc0);
    acc1 = wave_sum(acc1);

    if (lane == 0) {
        float rd = 1.f / (psum + EPS);
        float v0 = acc0 * rd + b2[0];
        float v1 = acc1 * rd + b2[1];
        float mx = fmaxf(v0, v1);
        float lse = mx + logf(__expf(v0 - mx) + __expf(v1 - mx));
        out[2 * n] = v0 - lse;
        out[2 * n + 1] = v1 - lse;
    }
}

extern "C" void kernel_launch(void* const* d_in, const int* in_sizes, int n_in,
                              void* d_out, int out_size, void* d_ws, size_t ws_size,
                              hipStream_t stream) {
    const float* x      = (const float*)d_in[0];
    const int*   eidx   = (const int*)d_in[1];
    const float* W1     = (const float*)d_in[2];
    const float* att_s1 = (const float*)d_in[3];
    const float* att_d1 = (const float*)d_in[4];
    const float* b1     = (const float*)d_in[5];
    const float* W2     = (const float*)d_in[6];
    const float* att_s2 = (const float*)d_in[7];
    const float* att_d2 = (const float*)d_in[8];
    const float* b2     = (const float*)d_in[9];

    const int N    = in_sizes[0] / 2;   // x is [N,2]
    const int E    = in_sizes[1] / 2;   // edge_index is [2,E]
    const int Etot = E + N;             // + self loops
    const int nb   = (N + SCAN_B - 1) / SCAN_B;   // <= 1024

    const int* src = eidx;
    const int* dst = eidx + E;

    // ---- workspace carve-up ----
    char* w = (char*)d_ws;
    int*    deg     = (int*)w;      w += (size_t)N * 4;
    int*    cursor  = (int*)w;      w += (size_t)N * 4;
    int*    incl    = (int*)w;      w += (size_t)N * 4;
    int*    bsum    = (int*)w;      w += (size_t)1024 * 4;
    int*    rowptr  = (int*)w;      w += (size_t)(N + 1) * 4;
    w = (char*)(((uintptr_t)w + 15) & ~(uintptr_t)15);
    int*    csr_src = (int*)w;      w += (size_t)Etot * 4;
    w = (char*)(((uintptr_t)w + 15) & ~(uintptr_t)15);
    float4* pack1   = (float4*)w;   w += (size_t)N * 16;
    float4* pack2   = (float4*)w;   w += (size_t)N * 16;
    float*  out     = (float*)d_out;

    hipMemsetAsync(deg, 0, (size_t)N * 2 * 4, stream);  // deg + cursor

    const int B = 256;
    dim3 blk(B);
    auto g1 = [&](long long t) { return dim3((unsigned)((t + B - 1) / B)); };

    // ---- CSR build ----
    deg_kernel<<<g1(Etot), blk, 0, stream>>>(dst, deg, E, Etot);
    scan_block_kernel<<<dim3(nb), dim3(SCAN_B), 0, stream>>>(deg, incl, bsum, N);
    scan_partials_kernel<<<dim3(1), dim3(1024), 0, stream>>>(bsum, nb);
    rowptr_kernel<<<g1(N + 1), blk, 0, stream>>>(deg, incl, bsum, rowptr, N, Etot);
    scatter_kernel<<<g1(Etot), blk, 0, stream>>>(src, dst, rowptr, cursor, csr_src, E, Etot);

    // ---- layer 1 node transform ----
    node1_kernel<<<g1((long long)N * 64), blk, 0, stream>>>(
        x, W1, att_s1, att_d1, pack1, N);

    // ---- fused layer-1 agg + layer-2 node transform ----
    fused_agg1_kernel<<<g1((long long)N * 64), blk, 0, stream>>>(
        rowptr, csr_src, pack1, W1, b1, W2, att_s2, att_d2, pack2, N);

    // ---- fused layer-2 agg + bias + log_softmax ----
    fused_agg2_kernel<<<g1((long long)N * 64), blk, 0, stream>>>(
        rowptr, csr_src, pack2, b2, out, N);
}